// Round 1
// baseline (159.053 us; speedup 1.0000x reference)
//
#include <hip/hip_runtime.h>
#include <math.h>

// Problem constants (B=64, J=17, H=W=128)
#define BJ    1088               // B*J maps per tensor
#define NMAP  (2 * BJ)           // 2176 maps (pred then gt)
#define HW    16384              // 128*128
#define NTH   512                // 8 waves per block
#define NWAVE (NTH / 64)
#define F4PT  (HW / 4 / NTH)     // 8 float4 per thread

// Monotonic unsigned key for float bits: orders like float compare.
__device__ __forceinline__ unsigned int ford(unsigned int u) {
    return (u & 0x80000000u) ? ~u : (u | 0x80000000u);
}
__device__ __forceinline__ unsigned int ford_inv(unsigned int o) {
    return (o & 0x80000000u) ? (o & 0x7fffffffu) : ~o;
}

// R9: drop the 64 KB LDS staging (R4-R7 structure). Theory: the staging
// bought "guaranteed one HBM sweep" at the cost of 2-blocks/CU occupancy and
// strict load->compute serialization per block (memory duty cycle ~55%,
// effective 2.7 TB/s vs 3.25 probe floor). A post-barrier re-materialization
// of v[] is an L1/L2/L3 hit, not an HBM re-read (FETCH counts HBM only), so
// the staging protects against traffic that is already cheap.
// No big LDS + __launch_bounds__(512,8) (VGPR cap 64; kernel is 52) gives
// 4 blocks/CU = 32 waves/CU: blocks in load phase hide the VALU sum tails of
// blocks past the barrier, and per-CU in-flight load bytes rise ~4x.
__global__ __launch_bounds__(NTH, 8) void hm_stats(const float* __restrict__ outp,
                                                   const float* __restrict__ tgtp,
                                                   float* __restrict__ d)
{
    __shared__ unsigned long long rk[NWAVE];
    __shared__ float rs[NWAVE], rc[NWAVE];

    const int m = blockIdx.x;                      // [0, NMAP)
    const int t = threadIdx.x;
    const float* __restrict__ src = (m < BJ)
        ? (outp + (size_t)m * HW)
        : (tgtp + (size_t)(m - BJ) * HW);
    const float4* __restrict__ s4 = (const float4*)src;

    // ---- single load burst (8 float4 outstanding), 4-chain max scan
    float4 v[F4PT];
#pragma unroll
    for (int k = 0; k < F4PT; ++k) v[k] = s4[t + k * NTH];

    float mx0 = -INFINITY, mx1 = -INFINITY, mx2 = -INFINITY, mx3 = -INFINITY;
    int   ix0 = 0, ix1 = 1, ix2 = 2, ix3 = 3;
#pragma unroll
    for (int k = 0; k < F4PT; ++k) {               // per-thread idx grows with k -> '>' keeps first
        const int base = (t + k * NTH) << 2;
        if (v[k].x > mx0) { mx0 = v[k].x; ix0 = base;     }
        if (v[k].y > mx1) { mx1 = v[k].y; ix1 = base + 1; }
        if (v[k].z > mx2) { mx2 = v[k].z; ix2 = base + 2; }
        if (v[k].w > mx3) { mx3 = v[k].w; ix3 = base + 3; }
    }

    // merge 4 chains via u64 keys: (ord(val)<<32)|~idx — max = (max val, min idx)
    unsigned long long k0 = ((unsigned long long)ford(__float_as_uint(mx0)) << 32) | (unsigned int)~ix0;
    unsigned long long k1 = ((unsigned long long)ford(__float_as_uint(mx1)) << 32) | (unsigned int)~ix1;
    unsigned long long k2 = ((unsigned long long)ford(__float_as_uint(mx2)) << 32) | (unsigned int)~ix2;
    unsigned long long k3 = ((unsigned long long)ford(__float_as_uint(mx3)) << 32) | (unsigned int)~ix3;
    unsigned long long key = k0 > k1 ? k0 : k1;
    key = k2 > key ? k2 : key;
    key = k3 > key ? k3 : key;
#pragma unroll
    for (int off = 32; off >= 1; off >>= 1) {
        const unsigned long long ok = __shfl_xor(key, off, 64);
        key = (ok > key) ? ok : key;
    }
    const int wave = t >> 6, lane = t & 63;
    if (lane == 0) rk[wave] = key;
    __syncthreads();                               // tiny-LDS barrier only
    unsigned long long bkey = rk[0];
#pragma unroll
    for (int w = 1; w < NWAVE; ++w) bkey = (rk[w] > bkey) ? rk[w] : bkey;

    const float maxv = __uint_as_float(ford_inv((unsigned int)(bkey >> 32)));
    const int   midx = (int)~(unsigned int)(bkey & 0xffffffffu);
    const float ym  = (float)(midx >> 7);          // reference: idx // H (H=128 stride)
    const float xm  = (float)(midx & 127);
    const float thv = maxv * 0.5f;

    // ---- masked distance sum from v[] (register-kept; compiler may
    // rematerialize via cache-hit reloads — both are fine, neither is HBM)
    float s = 0.0f, c = 0.0f;
#pragma unroll
    for (int k = 0; k < F4PT; ++k) {
        const float4 w = v[k];
        const int g4 = t + k * NTH;
        const float dy  = (float)(g4 >> 5) - ym;   // all 4 elems share a row
        const float dy2 = dy * dy;
        const float cb  = (float)((g4 << 2) & 127) - xm;
        {
            const float dx = cb;        const float ds = __builtin_amdgcn_sqrtf(fmaf(dx, dx, dy2));
            const float mk = (w.x > thv) ? 1.0f : 0.0f;  s = fmaf(mk, ds, s);  c += mk;
        }
        {
            const float dx = cb + 1.0f; const float ds = __builtin_amdgcn_sqrtf(fmaf(dx, dx, dy2));
            const float mk = (w.y > thv) ? 1.0f : 0.0f;  s = fmaf(mk, ds, s);  c += mk;
        }
        {
            const float dx = cb + 2.0f; const float ds = __builtin_amdgcn_sqrtf(fmaf(dx, dx, dy2));
            const float mk = (w.z > thv) ? 1.0f : 0.0f;  s = fmaf(mk, ds, s);  c += mk;
        }
        {
            const float dx = cb + 3.0f; const float ds = __builtin_amdgcn_sqrtf(fmaf(dx, dx, dy2));
            const float mk = (w.w > thv) ? 1.0f : 0.0f;  s = fmaf(mk, ds, s);  c += mk;
        }
    }

#pragma unroll
    for (int off = 32; off >= 1; off >>= 1) {
        s += __shfl_xor(s, off, 64);
        c += __shfl_xor(c, off, 64);
    }
    if (lane == 0) { rs[wave] = s; rc[wave] = c; }
    __syncthreads();
    if (t == 0) {
#pragma unroll
        for (int w = 1; w < NWAVE; ++w) { s += rs[w]; c += rc[w]; }
        const float mean = s / fmaxf(c, 1.0f);
        const float dd   = (c > 0.0f) ? (mean / 181.02f) : 1.0f;   // MAX_DIST
        d[m] = (maxv > 0.0f) ? dd : 0.0f;
    }
}

// Single-block final reduction: sum |gt - pred| / J / B
__global__ __launch_bounds__(256) void finalize(const float* __restrict__ d,
                                                float* __restrict__ out)
{
    __shared__ float rs[4];
    const int t = threadIdx.x;
    float acc = 0.0f;
    for (int i = t; i < BJ; i += 256)
        acc += fabsf(d[BJ + i] - d[i]);
#pragma unroll
    for (int off = 32; off >= 1; off >>= 1)
        acc += __shfl_down(acc, off, 64);
    const int wave = t >> 6, lane = t & 63;
    if (lane == 0) rs[wave] = acc;
    __syncthreads();
    if (t == 0) {
        acc = rs[0] + rs[1] + rs[2] + rs[3];
        out[0] = acc / 17.0f / 64.0f;              // / J / B, reference order
    }
}

extern "C" void kernel_launch(void* const* d_in, const int* in_sizes, int n_in,
                              void* d_out, int out_size, void* d_ws, size_t ws_size,
                              hipStream_t stream) {
    const float* outp = (const float*)d_in[0];     // [64,17,128,128] f32
    const float* tgtp = (const float*)d_in[1];
    float* d = (float*)d_ws;                       // NMAP floats

    hm_stats<<<dim3(NMAP), dim3(NTH), 0, stream>>>(outp, tgtp, d);
    finalize<<<dim3(1),    dim3(256), 0, stream>>>(d, (float*)d_out);
}